// Round 12
// baseline (281.925 us; speedup 1.0000x reference)
//
#include <hip/hip_runtime.h>

#define INPUT_SIZE 128
#define OUTPUT_SIZE 128
#define HIDDEN 8
#define BATCH 1024

#define ICH 32                   // i-chunks (blockIdx.y) -> 4096 blocks
#define IPC (INPUT_SIZE / ICH)   // 4 i's per chunk
#define TPB 128                  // threads per block (2 waves)
#define BPT 8                    // batch elements per thread
#define SLOT 60                  // dwords per i-slot: w1h2@0 b1h2@4 b2@8 w3@16 b3@24 W2h@28..59

typedef __fp16 half2v __attribute__((ext_vector_type(2)));

// Force a value to stay live in a VGPR: the asm result cannot be
// rematerialized, so the compiler cannot re-read the source from LDS.
#define PINU(x) asm volatile("" : "+v"(x))

#if defined(__has_builtin)
#if __has_builtin(__builtin_amdgcn_fdot2)
#define HAS_FDOT2 1
#endif
#endif
#ifndef HAS_FDOT2
#define HAS_FDOT2 0
#endif

static __device__ __forceinline__ half2v bch2(unsigned int u) {
    return __builtin_bit_cast(half2v, u);
}

// ---------------------------------------------------------------------------
// Prep: blocks 0..127 transpose x; 128..1151 W2 fp32->f16; 1152..1279 pack W1;
// 1280..1407 pack b1.
// ---------------------------------------------------------------------------
__global__ void prep_kernel(const float* __restrict__ x,
                            const float* __restrict__ W1,
                            const float* __restrict__ b1,
                            const float* __restrict__ W2,
                            float* __restrict__ xT,
                            unsigned int* __restrict__ W1h,
                            unsigned int* __restrict__ b1h,
                            __fp16* __restrict__ W2h) {
    const int bx = blockIdx.x;
    if (bx < 128) {
        __shared__ float tile[32][33];
        const int i0 = (bx & 3) * 32;
        const int b0 = (bx >> 2) * 32;
        const int tx = threadIdx.x & 31;
        const int ty = threadIdx.x >> 5;
#pragma unroll
        for (int r = ty; r < 32; r += 8)
            tile[r][tx] = x[(b0 + r) * INPUT_SIZE + (i0 + tx)];
        __syncthreads();
#pragma unroll
        for (int r = ty; r < 32; r += 8)
            xT[(i0 + r) * BATCH + (b0 + tx)] = tile[tx][r];
    } else if (bx < 1152) {
        const size_t idx = (size_t)(bx - 128) * 256 + threadIdx.x;
        const float4 v = *(const float4*)(W2 + 4 * idx);
        const half2v a = __builtin_amdgcn_cvt_pkrtz(v.x, v.y);
        const half2v b = __builtin_amdgcn_cvt_pkrtz(v.z, v.w);
        float2 st;
        st.x = __builtin_bit_cast(float, a);
        st.y = __builtin_bit_cast(float, b);
        *(float2*)(W2h + 4 * idx) = st;
    } else if (bx < 1280) {
        const size_t t = (size_t)(bx - 1152) * 256 + threadIdx.x;  // 32768 float4s
        const float4 v = *(const float4*)(W1 + 4 * t);
        W1h[2 * t]     = __builtin_bit_cast(unsigned int, __builtin_amdgcn_cvt_pkrtz(v.x, v.y));
        W1h[2 * t + 1] = __builtin_bit_cast(unsigned int, __builtin_amdgcn_cvt_pkrtz(v.z, v.w));
    } else {
        const size_t t = (size_t)(bx - 1280) * 256 + threadIdx.x;
        const float4 v = *(const float4*)(b1 + 4 * t);
        b1h[2 * t]     = __builtin_bit_cast(unsigned int, __builtin_amdgcn_cvt_pkrtz(v.x, v.y));
        b1h[2 * t + 1] = __builtin_bit_cast(unsigned int, __builtin_amdgcn_cvt_pkrtz(v.z, v.w));
    }
}

// ---------------------------------------------------------------------------
// Main kernel. block=(o,ic). Stage IPC weight slots in LDS once; per i load
// all weights -> VGPR, PIN them (no rematerialized LDS re-reads), run two
// 4-batch halves of packed-f16 L1 + fdot2 L2 + fp32 L3. atomicAdd epilogue.
// ---------------------------------------------------------------------------
__global__ __launch_bounds__(TPB, 4)
void mlpkan_kernel(const float* __restrict__ xT,
                   const unsigned int* __restrict__ W1h,
                   const unsigned int* __restrict__ b1h,
                   const __fp16* __restrict__ W2h, const float* __restrict__ b2,
                   const float* __restrict__ W3, const float* __restrict__ b3,
                   float* __restrict__ out) {
    __shared__ float wlds[IPC * SLOT];

    const int o   = blockIdx.x;
    const int ic  = blockIdx.y;
    const int tid = threadIdx.x;

    // ---- stage weights: 16 threads per i-slot ----
    {
        const int ii  = tid >> 4;
        const int idx = tid & 15;
        if (ii < IPC) {
            const int n = (ic * IPC + ii) * OUTPUT_SIZE + o;
            float* d = &wlds[ii * SLOT];
            if (idx == 0)      *(float4*)(d + 0)  = *(const float4*)((const float*)W1h + (size_t)n * 4);
            else if (idx == 1) *(float4*)(d + 4)  = *(const float4*)((const float*)b1h + (size_t)n * 4);
            else if (idx == 2) *(float4*)(d + 8)  = *(const float4*)(b2 + (size_t)n * 8);
            else if (idx == 3) *(float4*)(d + 12) = *(const float4*)(b2 + (size_t)n * 8 + 4);
            else if (idx == 4) *(float4*)(d + 16) = *(const float4*)(W3 + (size_t)n * 8);
            else if (idx == 5) *(float4*)(d + 20) = *(const float4*)(W3 + (size_t)n * 8 + 4);
            else if (idx == 6) d[24] = b3[n];
            else if (idx >= 8) *(float4*)(d + 28 + 4 * (idx - 8)) =
                *(const float4*)((const char*)W2h + (size_t)n * 128 + (idx - 8) * 16);
        }
    }
    __syncthreads();

    float acc[BPT];
#pragma unroll
    for (int j = 0; j < BPT; ++j) acc[j] = 0.0f;

#pragma unroll 1
    for (int ii = 0; ii < IPC; ++ii) {
        const int i = ic * IPC + ii;
        const float* w = &wlds[ii * SLOT];

        const float4 sA = *(const float4*)(xT + (size_t)i * BATCH + 4 * tid);
        const float4 sB = *(const float4*)(xT + (size_t)i * BATCH + 512 + 4 * tid);

        // ---- load ALL weights to VGPR and pin them live ----
        unsigned int w1u[4], b1u[4];
        {
            const uint4 a = *(const uint4*)(w + 0);
            const uint4 b = *(const uint4*)(w + 4);
            w1u[0] = a.x; w1u[1] = a.y; w1u[2] = a.z; w1u[3] = a.w;
            b1u[0] = b.x; b1u[1] = b.y; b1u[2] = b.z; b1u[3] = b.w;
        }
#pragma unroll
        for (int q = 0; q < 4; ++q) { PINU(w1u[q]); PINU(b1u[q]); }

        float b2r[8], w3r[8];
        {
            const float4 a = *(const float4*)(w + 8);
            const float4 b = *(const float4*)(w + 12);
            const float4 c = *(const float4*)(w + 16);
            const float4 d = *(const float4*)(w + 20);
            b2r[0] = a.x; b2r[1] = a.y; b2r[2] = a.z; b2r[3] = a.w;
            b2r[4] = b.x; b2r[5] = b.y; b2r[6] = b.z; b2r[7] = b.w;
            w3r[0] = c.x; w3r[1] = c.y; w3r[2] = c.z; w3r[3] = c.w;
            w3r[4] = d.x; w3r[5] = d.y; w3r[6] = d.z; w3r[7] = d.w;
        }
#pragma unroll
        for (int q = 0; q < 8; ++q) { PINU(b2r[q]); PINU(w3r[q]); }
        float b3r = w[24];
        PINU(b3r);

        unsigned int w2u[32];
#pragma unroll
        for (int r = 0; r < 8; ++r) {
            const uint4 row = *(const uint4*)(w + 28 + 4 * r);
            w2u[4 * r + 0] = row.x; w2u[4 * r + 1] = row.y;
            w2u[4 * r + 2] = row.z; w2u[4 * r + 3] = row.w;
        }
#pragma unroll
        for (int q = 0; q < 32; ++q) PINU(w2u[q]);

        const half2v zero2 = {(__fp16)0.0f, (__fp16)0.0f};

        // ---- two halves of 4 batches each ----
#pragma unroll
        for (int jh = 0; jh < 2; ++jh) {
            const float4 sv = jh ? sB : sA;
            const float sjs[4] = {sv.x, sv.y, sv.z, sv.w};

            half2v h1p[4][4];
#pragma unroll
            for (int j = 0; j < 4; ++j) {
                const half2v xx = __builtin_amdgcn_cvt_pkrtz(sjs[j], sjs[j]);
#pragma unroll
                for (int q = 0; q < 4; ++q) {
                    const half2v v = bch2(w1u[q]) * xx + bch2(b1u[q]);  // v_pk_fma_f16
                    h1p[j][q] = __builtin_elementwise_max(v, zero2);    // v_pk_max_f16
                }
            }

#pragma unroll
            for (int j = 0; j < 4; ++j) {
                float h2[8];
#if HAS_FDOT2
#pragma unroll
                for (int h = 0; h < 8; ++h) {
                    float v = b2r[h];
#pragma unroll
                    for (int q = 0; q < 4; ++q)
                        v = __builtin_amdgcn_fdot2(bch2(w2u[4 * h + q]), h1p[j][q], v, false);
                    h2[h] = fmaxf(v, 0.0f);
                }
#else
#pragma unroll
                for (int h = 0; h < 8; ++h) {
                    float v = b2r[h];
#pragma unroll
                    for (int q = 0; q < 4; ++q) {
                        const half2v wv = bch2(w2u[4 * h + q]);
                        v = fmaf((float)wv[0], (float)h1p[j][q][0], v);
                        v = fmaf((float)wv[1], (float)h1p[j][q][1], v);
                    }
                    h2[h] = fmaxf(v, 0.0f);
                }
#endif
                float v3 = b3r;
#pragma unroll
                for (int k = 0; k < 8; ++k)
                    v3 = fmaf(w3r[k], h2[k], v3);
                acc[jh * 4 + j] += v3;
            }
        }
    }

    // ---- atomic epilogue: out[b][o] += acc ----
#pragma unroll
    for (int j = 0; j < BPT; ++j) {
        const int b = (j < 4) ? (4 * tid + j) : (512 + 4 * tid + (j - 4));
        atomicAdd(&out[(size_t)b * OUTPUT_SIZE + o], acc[j]);
    }
}

// ---------------------------------------------------------------------------
// Fallback (ws too small — should never trigger with the observed 268MB ws):
// naive fp32 path, atomic epilogue.
// ---------------------------------------------------------------------------
__global__ __launch_bounds__(256, 2)
void mlpkan_naive(const float* __restrict__ x,
                  const float* __restrict__ W1, const float* __restrict__ b1,
                  const float* __restrict__ W2, const float* __restrict__ b2,
                  const float* __restrict__ W3, const float* __restrict__ b3,
                  float* __restrict__ out) {
    const int o = blockIdx.x;
    const int b = blockIdx.y * 256 + threadIdx.x;
    float acc = 0.0f;
    for (int i = 0; i < INPUT_SIZE; ++i) {
        const int n = i * OUTPUT_SIZE + o;
        const float s = x[b * INPUT_SIZE + i];
        float h1[8], h2[8];
#pragma unroll
        for (int k = 0; k < 8; ++k)
            h1[k] = fmaxf(fmaf(W1[(size_t)n * 8 + k], s, b1[(size_t)n * 8 + k]), 0.0f);
#pragma unroll
        for (int h = 0; h < 8; ++h) {
            float v = b2[(size_t)n * 8 + h];
#pragma unroll
            for (int k = 0; k < 8; ++k)
                v = fmaf(W2[(size_t)n * 64 + h * 8 + k], h1[k], v);
            h2[h] = fmaxf(v, 0.0f);
        }
        float v = b3[n];
#pragma unroll
        for (int k = 0; k < 8; ++k)
            v = fmaf(W3[(size_t)n * 8 + k], h2[k], v);
        acc += v;
    }
    out[(size_t)b * OUTPUT_SIZE + o] = acc;  // full sum per (b,o), no atomics needed
}

extern "C" void kernel_launch(void* const* d_in, const int* in_sizes, int n_in,
                              void* d_out, int out_size, void* d_ws, size_t ws_size,
                              hipStream_t stream) {
    const float* x  = (const float*)d_in[0];
    const float* W1 = (const float*)d_in[1];
    const float* b1 = (const float*)d_in[2];
    const float* W2 = (const float*)d_in[3];
    const float* b2 = (const float*)d_in[4];
    const float* W3 = (const float*)d_in[5];
    const float* b3 = (const float*)d_in[6];
    float* out = (float*)d_out;

    const size_t xt_elems  = (size_t)INPUT_SIZE * BATCH;               // 128K f
    const size_t w2h_bytes = (size_t)16384 * 64 * sizeof(__fp16);      // 2MB
    const size_t w1h_elems = (size_t)16384 * 4;                        // 64K uints
    const size_t need_bytes = xt_elems * sizeof(float) + w2h_bytes
                            + 2 * w1h_elems * sizeof(unsigned int);    // ~3MB

    if (ws_size >= need_bytes) {
        float*        xT  = (float*)d_ws;
        __fp16*       W2h = (__fp16*)(xT + xt_elems);
        unsigned int* W1h = (unsigned int*)((char*)W2h + w2h_bytes);
        unsigned int* b1h = W1h + w1h_elems;

        hipMemsetAsync(d_out, 0, (size_t)BATCH * OUTPUT_SIZE * sizeof(float), stream);
        prep_kernel<<<1408, 256, 0, stream>>>(x, W1, b1, W2, xT, W1h, b1h, W2h);
        mlpkan_kernel<<<dim3(OUTPUT_SIZE, ICH), TPB, 0, stream>>>(
            xT, W1h, b1h, W2h, b2, W3, b3, out);
    } else {
        mlpkan_naive<<<dim3(OUTPUT_SIZE, BATCH / 256), 256, 0, stream>>>(
            x, W1, b1, W2, b2, W3, b3, out);
    }
}

// Round 13
// 110.206 us; speedup vs baseline: 2.5582x; 2.5582x over previous
//
#include <hip/hip_runtime.h>

#define INPUT_SIZE 128
#define OUTPUT_SIZE 128
#define HIDDEN 8
#define BATCH 1024

#define ICH 32                   // i-chunks (blockIdx.y) -> 4096 blocks
#define IPC (INPUT_SIZE / ICH)   // 4 i's per chunk
#define TPB 128                  // threads per block (2 waves)
#define BPT 8                    // batch elements per thread
#define SLOT 60                  // dwords per i-slot: w1h2@0 b1h2@4 b2@8 w3@16 b3@24 W2h@28..59

typedef __fp16 half2v __attribute__((ext_vector_type(2)));

#if defined(__has_builtin)
#if __has_builtin(__builtin_amdgcn_fdot2)
#define HAS_FDOT2 1
#endif
#endif
#ifndef HAS_FDOT2
#define HAS_FDOT2 0
#endif

static __device__ __forceinline__ half2v bch2(unsigned int u) {
    return __builtin_bit_cast(half2v, u);
}
static __device__ __forceinline__ unsigned int rflu(unsigned int u) {
    return (unsigned int)__builtin_amdgcn_readfirstlane((int)u);
}
static __device__ __forceinline__ float rflf(float f) {
    return __builtin_bit_cast(float,
        __builtin_amdgcn_readfirstlane(__builtin_bit_cast(int, f)));
}

// ---------------------------------------------------------------------------
// Prep: blocks 0..127 transpose x; 128..1151 W2 fp32->f16; 1152..1279 pack W1;
// 1280..1407 pack b1.
// ---------------------------------------------------------------------------
__global__ void prep_kernel(const float* __restrict__ x,
                            const float* __restrict__ W1,
                            const float* __restrict__ b1,
                            const float* __restrict__ W2,
                            float* __restrict__ xT,
                            unsigned int* __restrict__ W1h,
                            unsigned int* __restrict__ b1h,
                            __fp16* __restrict__ W2h) {
    const int bx = blockIdx.x;
    if (bx < 128) {
        __shared__ float tile[32][33];
        const int i0 = (bx & 3) * 32;
        const int b0 = (bx >> 2) * 32;
        const int tx = threadIdx.x & 31;
        const int ty = threadIdx.x >> 5;
#pragma unroll
        for (int r = ty; r < 32; r += 8)
            tile[r][tx] = x[(b0 + r) * INPUT_SIZE + (i0 + tx)];
        __syncthreads();
#pragma unroll
        for (int r = ty; r < 32; r += 8)
            xT[(i0 + r) * BATCH + (b0 + tx)] = tile[tx][r];
    } else if (bx < 1152) {
        const size_t idx = (size_t)(bx - 128) * 256 + threadIdx.x;
        const float4 v = *(const float4*)(W2 + 4 * idx);
        const half2v a = __builtin_amdgcn_cvt_pkrtz(v.x, v.y);
        const half2v b = __builtin_amdgcn_cvt_pkrtz(v.z, v.w);
        float2 st;
        st.x = __builtin_bit_cast(float, a);
        st.y = __builtin_bit_cast(float, b);
        *(float2*)(W2h + 4 * idx) = st;
    } else if (bx < 1280) {
        const size_t t = (size_t)(bx - 1152) * 256 + threadIdx.x;  // 32768 float4s
        const float4 v = *(const float4*)(W1 + 4 * t);
        W1h[2 * t]     = __builtin_bit_cast(unsigned int, __builtin_amdgcn_cvt_pkrtz(v.x, v.y));
        W1h[2 * t + 1] = __builtin_bit_cast(unsigned int, __builtin_amdgcn_cvt_pkrtz(v.z, v.w));
    } else {
        const size_t t = (size_t)(bx - 1280) * 256 + threadIdx.x;
        const float4 v = *(const float4*)(b1 + 4 * t);
        b1h[2 * t]     = __builtin_bit_cast(unsigned int, __builtin_amdgcn_cvt_pkrtz(v.x, v.y));
        b1h[2 * t + 1] = __builtin_bit_cast(unsigned int, __builtin_amdgcn_cvt_pkrtz(v.z, v.w));
    }
}

// ---------------------------------------------------------------------------
// Main kernel. block=(o,ic). Stage IPC weight slots in LDS once. Per i:
// LDS-broadcast-read the block-uniform weights, readfirstlane them into
// SGPRs (w1, w2, w3 — SGPR file has room, so no rematerialization pressure),
// keep b1/b2/b3 in VGPRs (1-SGPR-operand-per-inst rule). Inner loops are
// v_pk_fma/v_dot2/v_fmac with SGPR weight operands; VGPR live-set ~70.
// Partials epilogue (atomics were a 170us regression in r12).
// ---------------------------------------------------------------------------
template <bool PARTIALS>
__global__ __launch_bounds__(TPB, 4)
void mlpkan_kernel(const float* __restrict__ xT,
                   const unsigned int* __restrict__ W1h,
                   const unsigned int* __restrict__ b1h,
                   const __fp16* __restrict__ W2h, const float* __restrict__ b2,
                   const float* __restrict__ W3, const float* __restrict__ b3,
                   float* __restrict__ partials, float* __restrict__ out) {
    __shared__ float wlds[IPC * SLOT];

    const int o   = blockIdx.x;
    const int ic  = blockIdx.y;
    const int tid = threadIdx.x;

    // ---- stage weights: 16 threads per i-slot ----
    {
        const int ii  = tid >> 4;
        const int idx = tid & 15;
        if (ii < IPC) {
            const int n = (ic * IPC + ii) * OUTPUT_SIZE + o;
            float* d = &wlds[ii * SLOT];
            if (idx == 0)      *(float4*)(d + 0)  = *(const float4*)((const float*)W1h + (size_t)n * 4);
            else if (idx == 1) *(float4*)(d + 4)  = *(const float4*)((const float*)b1h + (size_t)n * 4);
            else if (idx == 2) *(float4*)(d + 8)  = *(const float4*)(b2 + (size_t)n * 8);
            else if (idx == 3) *(float4*)(d + 12) = *(const float4*)(b2 + (size_t)n * 8 + 4);
            else if (idx == 4) *(float4*)(d + 16) = *(const float4*)(W3 + (size_t)n * 8);
            else if (idx == 5) *(float4*)(d + 20) = *(const float4*)(W3 + (size_t)n * 8 + 4);
            else if (idx == 6) d[24] = b3[n];
            else if (idx >= 8) *(float4*)(d + 28 + 4 * (idx - 8)) =
                *(const float4*)((const char*)W2h + (size_t)n * 128 + (idx - 8) * 16);
        }
    }
    __syncthreads();

    float acc[BPT];
#pragma unroll
    for (int j = 0; j < BPT; ++j) acc[j] = 0.0f;

#pragma unroll 1
    for (int ii = 0; ii < IPC; ++ii) {
        const int i = ic * IPC + ii;
        const float* w = &wlds[ii * SLOT];

        const float4 sA = *(const float4*)(xT + (size_t)i * BATCH + 4 * tid);
        const float4 sB = *(const float4*)(xT + (size_t)i * BATCH + 512 + 4 * tid);

        // ---- weights -> SGPRs via readfirstlane (block-uniform) ----
        unsigned int sw1[4];
        {
            const uint4 a = *(const uint4*)(w + 0);
            sw1[0] = rflu(a.x); sw1[1] = rflu(a.y); sw1[2] = rflu(a.z); sw1[3] = rflu(a.w);
        }
        float sw3[8];
        {
            const float4 c = *(const float4*)(w + 16);
            const float4 d = *(const float4*)(w + 20);
            sw3[0] = rflf(c.x); sw3[1] = rflf(c.y); sw3[2] = rflf(c.z); sw3[3] = rflf(c.w);
            sw3[4] = rflf(d.x); sw3[5] = rflf(d.y); sw3[6] = rflf(d.z); sw3[7] = rflf(d.w);
        }
        unsigned int sw2[32];
#pragma unroll
        for (int r = 0; r < 8; ++r) {
            const uint4 row = *(const uint4*)(w + 28 + 4 * r);
            sw2[4 * r + 0] = rflu(row.x); sw2[4 * r + 1] = rflu(row.y);
            sw2[4 * r + 2] = rflu(row.z); sw2[4 * r + 3] = rflu(row.w);
        }

        // ---- biases stay in VGPRs (1 SGPR operand per VALU inst) ----
        const uint4  b1v = *(const uint4*)(w + 4);
        const half2v b1p[4] = {bch2(b1v.x), bch2(b1v.y), bch2(b1v.z), bch2(b1v.w)};
        const float4 b2a = *(const float4*)(w + 8);
        const float4 b2b = *(const float4*)(w + 12);
        const float b2r[8] = {b2a.x, b2a.y, b2a.z, b2a.w, b2b.x, b2b.y, b2b.z, b2b.w};
        const float b3r = w[24];

        const half2v zero2 = {(__fp16)0.0f, (__fp16)0.0f};

        // ---- two halves of 4 batches each (h1p live = 16 dwords) ----
#pragma unroll
        for (int jh = 0; jh < 2; ++jh) {
            const float4 sv = jh ? sB : sA;
            const float sjs[4] = {sv.x, sv.y, sv.z, sv.w};

            half2v h1p[4][4];
#pragma unroll
            for (int j = 0; j < 4; ++j) {
                const half2v xx = __builtin_amdgcn_cvt_pkrtz(sjs[j], sjs[j]);
#pragma unroll
                for (int q = 0; q < 4; ++q) {
                    const half2v v = bch2(sw1[q]) * xx + b1p[q];     // v_pk_fma_f16 (sgpr w1)
                    h1p[j][q] = __builtin_elementwise_max(v, zero2); // v_pk_max_f16
                }
            }

#pragma unroll
            for (int j = 0; j < 4; ++j) {
                float h2[8];
#if HAS_FDOT2
#pragma unroll
                for (int h = 0; h < 8; ++h) {
                    float v = b2r[h];
#pragma unroll
                    for (int q = 0; q < 4; ++q)
                        v = __builtin_amdgcn_fdot2(bch2(sw2[4 * h + q]), h1p[j][q], v, false);
                    h2[h] = fmaxf(v, 0.0f);
                }
#else
#pragma unroll
                for (int h = 0; h < 8; ++h) {
                    float v = b2r[h];
#pragma unroll
                    for (int q = 0; q < 4; ++q) {
                        const half2v wv = bch2(sw2[4 * h + q]);
                        v = fmaf((float)wv[0], (float)h1p[j][q][0], v);
                        v = fmaf((float)wv[1], (float)h1p[j][q][1], v);
                    }
                    h2[h] = fmaxf(v, 0.0f);
                }
#endif
                float v3 = b3r;
#pragma unroll
                for (int k = 0; k < 8; ++k)
                    v3 = fmaf(sw3[k], h2[k], v3);                    // v_fmac (sgpr w3)
                acc[jh * 4 + j] += v3;
            }
        }
    }

    if (PARTIALS) {
        float* base = partials + ((size_t)ic * OUTPUT_SIZE + o) * BATCH;
        float4 pa = {acc[0], acc[1], acc[2], acc[3]};
        float4 pb = {acc[4], acc[5], acc[6], acc[7]};
        *(float4*)(base + 4 * tid)       = pa;
        *(float4*)(base + 512 + 4 * tid) = pb;
    } else {
#pragma unroll
        for (int j = 0; j < BPT; ++j) {
            const int b = (j < 4) ? (4 * tid + j) : (512 + 4 * tid + (j - 4));
            atomicAdd(&out[(size_t)b * OUTPUT_SIZE + o], acc[j]);
        }
    }
}

// ---------------------------------------------------------------------------
// Reduce ICH partials [ic][o][b] -> out [b][o] with LDS transpose.
// ---------------------------------------------------------------------------
__global__ void reduce_kernel(const float* __restrict__ partials,
                              float* __restrict__ out) {
    __shared__ float tile[32][33];
    const int o0 = blockIdx.x * 32;
    const int b0 = blockIdx.y * 32;
    const int tx = threadIdx.x;
    const int ty = threadIdx.y;
#pragma unroll
    for (int r = ty; r < 32; r += 16) {
        float v = 0.0f;
#pragma unroll
        for (int icc = 0; icc < ICH; ++icc)
            v += partials[((size_t)icc * OUTPUT_SIZE + o0 + r) * BATCH + b0 + tx];
        tile[r][tx] = v;
    }
    __syncthreads();
#pragma unroll
    for (int r = ty; r < 32; r += 16)
        out[(size_t)(b0 + r) * OUTPUT_SIZE + o0 + tx] = tile[tx][r];
}

__global__ void zero_out_kernel(float* __restrict__ out, int n) {
    int idx = blockIdx.x * blockDim.x + threadIdx.x;
    if (idx < n) out[idx] = 0.0f;
}

extern "C" void kernel_launch(void* const* d_in, const int* in_sizes, int n_in,
                              void* d_out, int out_size, void* d_ws, size_t ws_size,
                              hipStream_t stream) {
    const float* x  = (const float*)d_in[0];
    const float* W1 = (const float*)d_in[1];
    const float* b1 = (const float*)d_in[2];
    const float* W2 = (const float*)d_in[3];
    const float* b2 = (const float*)d_in[4];
    const float* W3 = (const float*)d_in[5];
    const float* b3 = (const float*)d_in[6];
    float* out = (float*)d_out;

    const size_t xt_elems   = (size_t)INPUT_SIZE * BATCH;               // 128K f
    const size_t part_elems = (size_t)ICH * OUTPUT_SIZE * BATCH;        // 4M f
    const size_t w2h_bytes  = (size_t)16384 * 64 * sizeof(__fp16);      // 2MB
    const size_t w1h_elems  = (size_t)16384 * 4;                        // 64K uints
    const size_t need_bytes = (xt_elems + part_elems) * sizeof(float) + w2h_bytes
                            + 2 * w1h_elems * sizeof(unsigned int);     // ~21MB

    dim3 mgrid(OUTPUT_SIZE, ICH);

    if (ws_size >= need_bytes) {
        float*        xT       = (float*)d_ws;
        float*        partials = xT + xt_elems;
        __fp16*       W2h      = (__fp16*)(partials + part_elems);
        unsigned int* W1h      = (unsigned int*)((char*)W2h + w2h_bytes);
        unsigned int* b1h      = W1h + w1h_elems;

        prep_kernel<<<1408, 256, 0, stream>>>(x, W1, b1, W2, xT, W1h, b1h, W2h);
        mlpkan_kernel<true><<<mgrid, TPB, 0, stream>>>(xT, W1h, b1h, W2h, b2, W3, b3,
                                                       partials, out);
        dim3 rgrid(OUTPUT_SIZE / 32, BATCH / 32);
        reduce_kernel<<<rgrid, dim3(32, 16), 0, stream>>>(partials, out);
    } else {
        const int nz = BATCH * OUTPUT_SIZE;
        zero_out_kernel<<<(nz + 255) / 256, 256, 0, stream>>>(out, nz);
        if (ws_size >= xt_elems * sizeof(float) + w2h_bytes + 2 * w1h_elems * sizeof(unsigned int)) {
            float*        xT  = (float*)d_ws;
            __fp16*       W2h = (__fp16*)(xT + xt_elems);
            unsigned int* W1h = (unsigned int*)((char*)W2h + w2h_bytes);
            unsigned int* b1h = W1h + w1h_elems;
            prep_kernel<<<1408, 256, 0, stream>>>(x, W1, b1, W2, xT, W1h, b1h, W2h);
            mlpkan_kernel<false><<<mgrid, TPB, 0, stream>>>(xT, W1h, b1h, W2h, b2, W3, b3,
                                                            nullptr, out);
        }
    }
}

// Round 15
// 107.501 us; speedup vs baseline: 2.6225x; 1.0252x over previous
//
#include <hip/hip_runtime.h>

#define INPUT_SIZE 128
#define OUTPUT_SIZE 128
#define HIDDEN 8
#define BATCH 1024

#define ICH 32                   // i-chunks (blockIdx.y) -> 4096 blocks
#define IPC (INPUT_SIZE / ICH)   // 4 i's per chunk
#define TPB 128                  // threads per block (2 waves)
#define BPT 8                    // batch elements per thread
#define SLOT 60                  // dwords: w1h2@0 b1h2@4 b2@8 w3@16 b3@24 W2h@28..59

typedef __fp16 half2v __attribute__((ext_vector_type(2)));

#if defined(__has_builtin)
#if __has_builtin(__builtin_amdgcn_fdot2)
#define HAS_FDOT2 1
#endif
#endif
#ifndef HAS_FDOT2
#define HAS_FDOT2 0
#endif

static __device__ __forceinline__ half2v bch2(unsigned int u) {
    return __builtin_bit_cast(half2v, u);
}

// ---------------------------------------------------------------------------
// Prep: blocks 0..127 transpose x; 128..1151 W2 fp32->f16; 1152..1279 pack W1;
// 1280..1407 pack b1.
// ---------------------------------------------------------------------------
__global__ void prep_kernel(const float* __restrict__ x,
                            const float* __restrict__ W1,
                            const float* __restrict__ b1,
                            const float* __restrict__ W2,
                            float* __restrict__ xT,
                            unsigned int* __restrict__ W1h,
                            unsigned int* __restrict__ b1h,
                            __fp16* __restrict__ W2h) {
    const int bx = blockIdx.x;
    if (bx < 128) {
        __shared__ float tile[32][33];
        const int i0 = (bx & 3) * 32;
        const int b0 = (bx >> 2) * 32;
        const int tx = threadIdx.x & 31;
        const int ty = threadIdx.x >> 5;
#pragma unroll
        for (int r = ty; r < 32; r += 8)
            tile[r][tx] = x[(b0 + r) * INPUT_SIZE + (i0 + tx)];
        __syncthreads();
#pragma unroll
        for (int r = ty; r < 32; r += 8)
            xT[(i0 + r) * BATCH + (b0 + tx)] = tile[tx][r];
    } else if (bx < 1152) {
        const size_t idx = (size_t)(bx - 128) * 256 + threadIdx.x;
        const float4 v = *(const float4*)(W2 + 4 * idx);
        const half2v a = __builtin_amdgcn_cvt_pkrtz(v.x, v.y);
        const half2v b = __builtin_amdgcn_cvt_pkrtz(v.z, v.w);
        float2 st;
        st.x = __builtin_bit_cast(float, a);
        st.y = __builtin_bit_cast(float, b);
        *(float2*)(W2h + 4 * idx) = st;
    } else if (bx < 1280) {
        const size_t t = (size_t)(bx - 1152) * 256 + threadIdx.x;  // 32768 float4s
        const float4 v = *(const float4*)(W1 + 4 * t);
        W1h[2 * t]     = __builtin_bit_cast(unsigned int, __builtin_amdgcn_cvt_pkrtz(v.x, v.y));
        W1h[2 * t + 1] = __builtin_bit_cast(unsigned int, __builtin_amdgcn_cvt_pkrtz(v.z, v.w));
    } else {
        const size_t t = (size_t)(bx - 1280) * 256 + threadIdx.x;
        const float4 v = *(const float4*)(b1 + 4 * t);
        b1h[2 * t]     = __builtin_bit_cast(unsigned int, __builtin_amdgcn_cvt_pkrtz(v.x, v.y));
        b1h[2 * t + 1] = __builtin_bit_cast(unsigned int, __builtin_amdgcn_cvt_pkrtz(v.z, v.w));
    }
}

// ---------------------------------------------------------------------------
// Main kernel. block=(o,ic). Stage IPC weight slots in LDS once. Per i:
//  L1 (j-major): h1p[8][4] packed f16 — weights w1/b1 = 8 dwords.
//  L2+L3 FUSED (h-major): per h load only {W2row(4), b2h, w3h} = 6 dwords,
//  update v3[j] += w3h * relu(fdot2x4(row, h1p[j]) + b2h) for all 8 j.
//  h2 never materialized; bulk live state (h1p, v3) is computation-produced,
//  so the compiler's "re-read LDS instead of keeping live" heuristic has
//  nothing to re-read. This removes the ~570 inst/i re-load fat (r7 PMC).
// ---------------------------------------------------------------------------
template <bool PARTIALS>
__global__ __launch_bounds__(TPB, 4)
void mlpkan_kernel(const float* __restrict__ xT,
                   const unsigned int* __restrict__ W1h,
                   const unsigned int* __restrict__ b1h,
                   const __fp16* __restrict__ W2h, const float* __restrict__ b2,
                   const float* __restrict__ W3, const float* __restrict__ b3,
                   float* __restrict__ partials, float* __restrict__ out) {
    __shared__ float wlds[IPC * SLOT];

    const int o   = blockIdx.x;
    const int ic  = blockIdx.y;
    const int tid = threadIdx.x;

    // ---- stage weights: 16 threads per i-slot ----
    {
        const int ii  = tid >> 4;
        const int idx = tid & 15;
        if (ii < IPC) {
            const int n = (ic * IPC + ii) * OUTPUT_SIZE + o;
            float* d = &wlds[ii * SLOT];
            if (idx == 0)      *(float4*)(d + 0)  = *(const float4*)((const float*)W1h + (size_t)n * 4);
            else if (idx == 1) *(float4*)(d + 4)  = *(const float4*)((const float*)b1h + (size_t)n * 4);
            else if (idx == 2) *(float4*)(d + 8)  = *(const float4*)(b2 + (size_t)n * 8);
            else if (idx == 3) *(float4*)(d + 12) = *(const float4*)(b2 + (size_t)n * 8 + 4);
            else if (idx == 4) *(float4*)(d + 16) = *(const float4*)(W3 + (size_t)n * 8);
            else if (idx == 5) *(float4*)(d + 20) = *(const float4*)(W3 + (size_t)n * 8 + 4);
            else if (idx == 6) d[24] = b3[n];
            else if (idx >= 8) *(float4*)(d + 28 + 4 * (idx - 8)) =
                *(const float4*)((const char*)W2h + (size_t)n * 128 + (idx - 8) * 16);
        }
    }
    __syncthreads();

    float acc[BPT];
#pragma unroll
    for (int j = 0; j < BPT; ++j) acc[j] = 0.0f;

#pragma unroll 1
    for (int ii = 0; ii < IPC; ++ii) {
        const int i = ic * IPC + ii;
        const float* w = &wlds[ii * SLOT];

        const float4 sA = *(const float4*)(xT + (size_t)i * BATCH + 4 * tid);
        const float4 sB = *(const float4*)(xT + (size_t)i * BATCH + 512 + 4 * tid);
        const float sjs[BPT] = {sA.x, sA.y, sA.z, sA.w, sB.x, sB.y, sB.z, sB.w};

        // ---------------- layer 1 (j-major, packed f16) ----------------
        const uint4 w1v = *(const uint4*)(w + 0);
        const uint4 b1v = *(const uint4*)(w + 4);
        const unsigned int w1u[4] = {w1v.x, w1v.y, w1v.z, w1v.w};
        const unsigned int b1u[4] = {b1v.x, b1v.y, b1v.z, b1v.w};
        const half2v zero2 = {(__fp16)0.0f, (__fp16)0.0f};

        half2v h1p[BPT][4];
#pragma unroll
        for (int j = 0; j < BPT; ++j) {
            const half2v xx = __builtin_amdgcn_cvt_pkrtz(sjs[j], sjs[j]);
#pragma unroll
            for (int q = 0; q < 4; ++q) {
                const half2v v = bch2(w1u[q]) * xx + bch2(b1u[q]);   // v_pk_fma_f16
                h1p[j][q] = __builtin_elementwise_max(v, zero2);     // v_pk_max_f16
            }
        }

        // ---------------- layers 2+3 fused (h-major) ----------------
        float v3[BPT];
#pragma unroll
        for (int j = 0; j < BPT; ++j) v3[j] = 0.0f;

#pragma unroll
        for (int h = 0; h < HIDDEN; ++h) {
            const uint4 row = *(const uint4*)(w + 28 + 4 * h);   // W2 row h (8 f16)
            const float b2h = w[8 + h];
            const float w3h = w[16 + h];
#pragma unroll
            for (int j = 0; j < BPT; ++j) {
#if HAS_FDOT2
                float t = b2h;
                t = __builtin_amdgcn_fdot2(bch2(row.x), h1p[j][0], t, false);
                t = __builtin_amdgcn_fdot2(bch2(row.y), h1p[j][1], t, false);
                t = __builtin_amdgcn_fdot2(bch2(row.z), h1p[j][2], t, false);
                t = __builtin_amdgcn_fdot2(bch2(row.w), h1p[j][3], t, false);
#else
                float t = b2h;
                {
                    const half2v r0 = bch2(row.x), r1 = bch2(row.y);
                    const half2v r2 = bch2(row.z), r3 = bch2(row.w);
                    t = fmaf((float)r0[0], (float)h1p[j][0][0], t);
                    t = fmaf((float)r0[1], (float)h1p[j][0][1], t);
                    t = fmaf((float)r1[0], (float)h1p[j][1][0], t);
                    t = fmaf((float)r1[1], (float)h1p[j][1][1], t);
                    t = fmaf((float)r2[0], (float)h1p[j][2][0], t);
                    t = fmaf((float)r2[1], (float)h1p[j][2][1], t);
                    t = fmaf((float)r3[0], (float)h1p[j][3][0], t);
                    t = fmaf((float)r3[1], (float)h1p[j][3][1], t);
                }
#endif
                v3[j] = fmaf(w3h, fmaxf(t, 0.0f), v3[j]);
            }
        }

        const float b3r = w[24];
#pragma unroll
        for (int j = 0; j < BPT; ++j)
            acc[j] += v3[j] + b3r;
    }

    if (PARTIALS) {
        float* base = partials + ((size_t)ic * OUTPUT_SIZE + o) * BATCH;
        float4 pa = {acc[0], acc[1], acc[2], acc[3]};
        float4 pb = {acc[4], acc[5], acc[6], acc[7]};
        *(float4*)(base + 4 * tid)       = pa;
        *(float4*)(base + 512 + 4 * tid) = pb;
    } else {
#pragma unroll
        for (int j = 0; j < BPT; ++j) {
            const int b = (j < 4) ? (4 * tid + j) : (512 + 4 * tid + (j - 4));
            atomicAdd(&out[(size_t)b * OUTPUT_SIZE + o], acc[j]);
        }
    }
}

// ---------------------------------------------------------------------------
// Reduce ICH partials [ic][o][b] -> out [b][o] with LDS transpose.
// ---------------------------------------------------------------------------
__global__ void reduce_kernel(const float* __restrict__ partials,
                              float* __restrict__ out) {
    __shared__ float tile[32][33];
    const int o0 = blockIdx.x * 32;
    const int b0 = blockIdx.y * 32;
    const int tx = threadIdx.x;
    const int ty = threadIdx.y;
#pragma unroll
    for (int r = ty; r < 32; r += 16) {
        float v = 0.0f;
#pragma unroll
        for (int icc = 0; icc < ICH; ++icc)
            v += partials[((size_t)icc * OUTPUT_SIZE + o0 + r) * BATCH + b0 + tx];
        tile[r][tx] = v;
    }
    __syncthreads();
#pragma unroll
    for (int r = ty; r < 32; r += 16)
        out[(size_t)(b0 + r) * OUTPUT_SIZE + o0 + tx] = tile[tx][r];
}

__global__ void zero_out_kernel(float* __restrict__ out, int n) {
    int idx = blockIdx.x * blockDim.x + threadIdx.x;
    if (idx < n) out[idx] = 0.0f;
}

extern "C" void kernel_launch(void* const* d_in, const int* in_sizes, int n_in,
                              void* d_out, int out_size, void* d_ws, size_t ws_size,
                              hipStream_t stream) {
    const float* x  = (const float*)d_in[0];
    const float* W1 = (const float*)d_in[1];
    const float* b1 = (const float*)d_in[2];
    const float* W2 = (const float*)d_in[3];
    const float* b2 = (const float*)d_in[4];
    const float* W3 = (const float*)d_in[5];
    const float* b3 = (const float*)d_in[6];
    float* out = (float*)d_out;

    const size_t xt_elems   = (size_t)INPUT_SIZE * BATCH;               // 128K f
    const size_t part_elems = (size_t)ICH * OUTPUT_SIZE * BATCH;        // 4M f
    const size_t w2h_bytes  = (size_t)16384 * 64 * sizeof(__fp16);      // 2MB
    const size_t w1h_elems  = (size_t)16384 * 4;                        // 64K uints
    const size_t need_bytes = (xt_elems + part_elems) * sizeof(float) + w2h_bytes
                            + 2 * w1h_elems * sizeof(unsigned int);     // ~21MB

    dim3 mgrid(OUTPUT_SIZE, ICH);

    if (ws_size >= need_bytes) {
        float*        xT       = (float*)d_ws;
        float*        partials = xT + xt_elems;
        __fp16*       W2h      = (__fp16*)(partials + part_elems);
        unsigned int* W1h      = (unsigned int*)((char*)W2h + w2h_bytes);
        unsigned int* b1h      = W1h + w1h_elems;

        prep_kernel<<<1408, 256, 0, stream>>>(x, W1, b1, W2, xT, W1h, b1h, W2h);
        mlpkan_kernel<true><<<mgrid, TPB, 0, stream>>>(xT, W1h, b1h, W2h, b2, W3, b3,
                                                       partials, out);
        dim3 rgrid(OUTPUT_SIZE / 32, BATCH / 32);
        reduce_kernel<<<rgrid, dim3(32, 16), 0, stream>>>(partials, out);
    } else {
        const int nz = BATCH * OUTPUT_SIZE;
        zero_out_kernel<<<(nz + 255) / 256, 256, 0, stream>>>(out, nz);
        if (ws_size >= xt_elems * sizeof(float) + w2h_bytes + 2 * w1h_elems * sizeof(unsigned int)) {
            float*        xT  = (float*)d_ws;
            __fp16*       W2h = (__fp16*)(xT + xt_elems);
            unsigned int* W1h = (unsigned int*)((char*)W2h + w2h_bytes);
            unsigned int* b1h = W1h + w1h_elems;
            prep_kernel<<<1408, 256, 0, stream>>>(x, W1, b1, W2, xT, W1h, b1h, W2h);
            mlpkan_kernel<false><<<mgrid, TPB, 0, stream>>>(xT, W1h, b1h, W2h, b2, W3, b3,
                                                            nullptr, out);
        }
    }
}